// Round 19
// baseline (49.035 us; speedup 1.0000x reference)
//
#include <hip/hip_runtime.h>

#define BB 4
#define NN 16384
#define SS 2048
#define CC 64
#define NS 32
#define KK 33   // NS + 1 (fps_idx prepended)
#define OC 70   // 3 raw xyz + 3 centered xyz + 64 features
#define SCH 8   // s-chunk per main block (8 queries, 1 wave each)
#define GT 512  // main block threads
#define NC 10
#define NCELL 1000
#define CCAP 64          // fixed per-cell capacity (avg 16.4, Poisson tail ~0)
#define HCAP 128         // per-wave hit buffer (avg 62, ~8 sigma; exact fallback)
#define RPAD 0.100001f   // cell-range pad (covers fp rounding of d2 test)

// --- prevent fma contraction so d2 matches the np/jax fp32 reference ---
__device__ __forceinline__ float sq_nofma(float v) {
  float r = v * v;
  asm volatile("" : "+v"(r));
  return r;
}

__device__ __forceinline__ int cell1(float x) {
  int c = (int)(x * 10.0f);
  return c < 0 ? 0 : (c > 9 ? 9 : c);
}
__device__ __forceinline__ int cell3(float x, float y, float z) {
  return (cell1(z) * NC + cell1(y)) * NC + cell1(x);
}

// ---------------- legacy wave ball-query (fallback + overflow path) -------
__device__ __forceinline__ void ball_query_wave(
    const float* __restrict__ xb, float qx, float qy, float qz, int lane,
    int* out) {
  const float R2 = 0.01f;
  int cnt = 0;
  int firstIdx = 0;
  for (int base = 0; base < NN; base += 256) {
    float px[4], py[4], pz[4];
#pragma unroll
    for (int j = 0; j < 4; ++j) {
      int n = base + j * 64 + lane;
      const float* p = xb + n * 3;
      px[j] = p[0]; py[j] = p[1]; pz[j] = p[2];
    }
#pragma unroll
    for (int j = 0; j < 4; ++j) {
      float dx = px[j] - qx, dy = py[j] - qy, dz = pz[j] - qz;
      float d2 = sq_nofma(dx) + sq_nofma(dy);
      asm volatile("" : "+v"(d2));
      d2 = d2 + sq_nofma(dz);
      bool m = d2 < R2;
      unsigned long long bal = __ballot(m);
      if (cnt == 0 && bal) firstIdx = base + j * 64 + __builtin_ctzll(bal);
      int pos = cnt + (int)__popcll(bal & ((1ull << lane) - 1ull));
      if (m && pos < NS) out[pos] = base + j * 64 + lane;
      cnt += (int)__popcll(bal);
    }
    if (cnt >= NS) break;
  }
  if (cnt < NS) {
    int pad = (cnt == 0) ? 0 : firstIdx;
    if (lane >= cnt && lane < NS) out[lane] = pad;
  }
}

// ---------------- K1: float4 transpose + direct fixed-capacity scatter ----
// (verified R10-R14: build side + memset + gaps = ~11.6us total)
__global__ __launch_bounds__(256) void qg_tr_build(
    const float* __restrict__ xyz, const float* __restrict__ feat,
    float* __restrict__ featT, int* __restrict__ cnt, int* __restrict__ ovf,
    float4* __restrict__ ptsc) {
  __shared__ float tile[32 * 260];  // 32 rows, stride 260 (pad kills conflicts)
  const int bid = (int)blockIdx.x;
  const int tid = (int)threadIdx.x;
  const int b = bid >> 7;
  const int rest = bid & 127;
  const int n0 = (rest >> 1) << 8;  // 0,256,...,16128
  const int cc = rest & 1;
  const int c0 = cc << 5;  // 0 or 32
  const int wv = tid >> 6, lane = tid & 63;

  if (cc == 0) {  // direct scatter of this block's 256 points
    const int n = n0 + tid;
    const float* p = xyz + ((size_t)b * NN + n) * 3;
    float x = p[0], y = p[1], z = p[2];
    int cell = cell3(x, y, z);
    int pos = atomicAdd(&cnt[(b << 10) + cell], 1);
    if (pos < CCAP) {
      ptsc[((((size_t)b << 10) + cell) << 6) + pos] =
          make_float4(x, y, z, __int_as_float(n));
    } else {
      atomicOr(&ovf[b], 1);
    }
  }

  const float* fb = feat + ((size_t)b * CC + c0) * NN + n0;
#pragma unroll
  for (int rr = 0; rr < 8; ++rr) {
    int c = rr * 4 + wv;  // 0..31
    float4 v = *(const float4*)(fb + (size_t)c * NN + 4 * lane);
    *(float4*)&tile[c * 260 + 4 * lane] = v;
  }
  __syncthreads();
  const int c4 = lane & 7, m = lane >> 3;
  float4* oT = (float4*)(featT + ((size_t)b * NN + n0) * CC);
#pragma unroll
  for (int it = 0; it < 8; ++it) {
    int n = it * 32 + wv * 8 + m;  // 0..255
    float4 v;
    v.x = tile[(4 * c4 + 0) * 260 + n];
    v.y = tile[(4 * c4 + 1) * 260 + n];
    v.z = tile[(4 * c4 + 2) * 260 + n];
    v.w = tile[(4 * c4 + 3) * 260 + n];
    oT[(size_t)n * (CC / 4) + (c0 >> 2) + c4] = v;
  }
}

// ---------------- K2: fused cell ball-query + gather -----------------------
// 1024 blocks (XCD-swizzled), 8 queries/block, one wave per query with
// barrier-free private rank; phases 2/3 twice over s-halves reusing sf;
// phase-3 stores widened to float4.
__global__ __launch_bounds__(GT) void qg_main(
    const float* __restrict__ xyz, const float* __restrict__ nxyz,
    const float4* __restrict__ ptsc, const int* __restrict__ cnt,
    const int* __restrict__ ovf, const float* __restrict__ featT,
    const int* __restrict__ fps, float* __restrict__ out) {
  __shared__ float sf[CC][4 * KK + 1];  // [64][133] padded: 0 bank conflicts
  __shared__ int sidx[SCH * KK];        // 264
  __shared__ int hitbuf[8][HCAP];
  const int tid = (int)threadIdx.x;
  const int raw = (int)blockIdx.x;               // 0..1023
  const int blk = (raw & 7) * 128 + (raw >> 3);  // bijective: 1024 = 8*128
  const int b = blk >> 8;
  const int s0 = (blk & 255) * SCH;
  const int wv = tid >> 6, lane = tid & 63;
  const int q = b * SS + s0 + wv;  // one query per wave
  const float R2 = 0.01f;
  const float qx = nxyz[q * 3 + 0];
  const float qy = nxyz[q * 3 + 1];
  const float qz = nxyz[q * 3 + 2];
  int* hb = hitbuf[wv];
  int* qout = &sidx[wv * KK];
  const bool bad = ovf[b] != 0;

  // ---- phase 1: ball query, fully per-wave (no inter-wave sync) ----
  if (bad) {
    // cell-capacity overflow (prob ~0): exact legacy linear scan
    ball_query_wave(xyz + (size_t)b * NN * 3, qx, qy, qz, lane, qout + 1);
  } else {
    int lox = max(0, (int)floorf((qx - RPAD) * 10.f));
    int hix = min(9, (int)floorf((qx + RPAD) * 10.f));
    int loy = max(0, (int)floorf((qy - RPAD) * 10.f));
    int hiy = min(9, (int)floorf((qy + RPAD) * 10.f));
    int loz = max(0, (int)floorf((qz - RPAD) * 10.f));
    int hiz = min(9, (int)floorf((qz + RPAD) * 10.f));
    const int ncx = hix - lox + 1, ncy = hiy - loy + 1, ncz = hiz - loz + 1;
    const int ncell = ncx * ncy * ncz;  // 1..27

    // hoist: lane i < ncell owns cell i (row-major over z,y,x)
    const int* cntb = cnt + (b << 10);
    int cell_l = 0, cnt_l = 0;
    if (lane < ncell) {
      int iz = lane / (ncx * ncy);
      int r = lane - iz * ncx * ncy;
      int iy = r / ncx, ix = r - iy * ncx;
      cell_l = ((loz + iz) * NC + (loy + iy)) * NC + (lox + ix);
      cnt_l = cntb[cell_l];
    }

    const float4* pcb = ptsc + ((size_t)b << 16);
    const unsigned long long lt = (1ull << lane) - 1ull;
    const int slot = lane & 31;
    const int half = lane >> 5;  // 0: first cell of pair, 1: second
    const int npair = (ncell + 1) >> 1;
    int hcnt = 0;

#define PAIRLOAD(pp)                                                       \
  ({                                                                       \
    int pc_ = ((pp) < npair) ? (pp) : 0;                                   \
    int ca_ = __shfl(cell_l, 2 * pc_, 64);                                 \
    int cb_ = __shfl(cell_l, 2 * pc_ + 1, 64);                             \
    pcb[(((half ? cb_ : ca_)) << 6) + slot];                               \
  })

    float4 v0 = PAIRLOAD(0);
    float4 v1 = PAIRLOAD(1);
    for (int p = 0; p < npair; ++p) {
      float4 v = v0;
      v0 = v1;
      v1 = PAIRLOAD(p + 2);
      int m0 = __shfl(cnt_l, 2 * p, 64);
      int m1 = __shfl(cnt_l, 2 * p + 1, 64);
      int m = half ? m1 : m0;
      {
        float dx = v.x - qx, dy = v.y - qy, dz = v.z - qz;
        float d2 = sq_nofma(dx) + sq_nofma(dy);
        asm volatile("" : "+v"(d2));
        d2 = d2 + sq_nofma(dz);
        bool hit = (slot < m) && (d2 < R2);
        unsigned long long bal = __ballot(hit);
        if (hit) {
          int pos = hcnt + (int)__popcll(bal & lt);
          if (pos < HCAP) hb[pos] = __float_as_int(v.w);
        }
        hcnt += (int)__popcll(bal);
      }
      if (m0 > 32 || m1 > 32) {  // rare (P ~ 6e-5 per cell), wave-uniform
        int ca = __shfl(cell_l, 2 * p, 64);
        int cb = __shfl(cell_l, 2 * p + 1, 64);
        float4 w = pcb[(((half ? cb : ca)) << 6) + 32 + slot];
        float dx = w.x - qx, dy = w.y - qy, dz = w.z - qz;
        float d2 = sq_nofma(dx) + sq_nofma(dy);
        asm volatile("" : "+v"(d2));
        d2 = d2 + sq_nofma(dz);
        bool hit = (32 + slot < m) && (d2 < R2);
        unsigned long long bal = __ballot(hit);
        if (hit) {
          int pos = hcnt + (int)__popcll(bal & lt);
          if (pos < HCAP) hb[pos] = __float_as_int(w.w);
        }
        hcnt += (int)__popcll(bal);
      }
    }
#undef PAIRLOAD

    asm volatile("s_waitcnt lgkmcnt(0)" ::: "memory");  // hb visible wave-wide
    const int M = hcnt;  // wave-uniform (ballot-accumulated)
    if (M > HCAP) {
      // hit-buffer overflow safety net: exact legacy linear scan
      ball_query_wave(xyz + (size_t)b * NN * 3, qx, qy, qz, lane, qout + 1);
    } else {
      // rank by original index = output position (order-independent)
      int minv = 0x7fffffff;
      for (int i = lane; i < M; i += 64) {
        int hh = hb[i];
        minv = min(minv, hh);
        int rank = 0;
        for (int j = 0; j < M; ++j) rank += (hb[j] < hh) ? 1 : 0;
        if (rank < NS) qout[1 + rank] = hh;
      }
      if (M < NS) {
#pragma unroll
        for (int d = 1; d < 64; d <<= 1)
          minv = min(minv, __shfl_xor(minv, d, 64));
        int pad = (M == 0) ? 0 : minv;
        if (lane >= M && lane < NS) qout[1 + lane] = pad;
      }
    }
  }
  if (lane == 0) qout[0] = fps[q];
  __syncthreads();

  // ---- phases 2/3 twice over s-halves, reusing sf ----
  const size_t cstr = (size_t)SS * KK;
  const float4* fT4 = (const float4*)(featT + (size_t)b * NN * CC);
#pragma unroll
  for (int hf = 0; hf < 2; ++hf) {
    const int base = hf * 4 * KK;  // 0 or 132
    // gather features -> padded LDS (hoisted idx + 5 independent loads)
    {
      const int e = tid & 15;
      const int g = tid >> 4;  // 0..31
      const bool has4 = (g + 128) < 4 * KK;
      int n0_ = sidx[base + g];
      int n1_ = sidx[base + g + 32];
      int n2_ = sidx[base + g + 64];
      int n3_ = sidx[base + g + 96];
      int n4_ = has4 ? sidx[base + g + 128] : 0;
      float4 w0 = fT4[(size_t)n0_ * (CC / 4) + e];
      float4 w1 = fT4[(size_t)n1_ * (CC / 4) + e];
      float4 w2 = fT4[(size_t)n2_ * (CC / 4) + e];
      float4 w3 = fT4[(size_t)n3_ * (CC / 4) + e];
      float4 w4 = has4 ? fT4[(size_t)n4_ * (CC / 4) + e]
                       : make_float4(0.f, 0.f, 0.f, 0.f);
      sf[4 * e + 0][g] = w0.x;
      sf[4 * e + 1][g] = w0.y;
      sf[4 * e + 2][g] = w0.z;
      sf[4 * e + 3][g] = w0.w;
      sf[4 * e + 0][g + 32] = w1.x;
      sf[4 * e + 1][g + 32] = w1.y;
      sf[4 * e + 2][g + 32] = w1.z;
      sf[4 * e + 3][g + 32] = w1.w;
      sf[4 * e + 0][g + 64] = w2.x;
      sf[4 * e + 1][g + 64] = w2.y;
      sf[4 * e + 2][g + 64] = w2.z;
      sf[4 * e + 3][g + 64] = w2.w;
      sf[4 * e + 0][g + 96] = w3.x;
      sf[4 * e + 1][g + 96] = w3.y;
      sf[4 * e + 2][g + 96] = w3.z;
      sf[4 * e + 3][g + 96] = w3.w;
      if (has4) {
        sf[4 * e + 0][g + 128] = w4.x;
        sf[4 * e + 1][g + 128] = w4.y;
        sf[4 * e + 2][g + 128] = w4.z;
        sf[4 * e + 3][g + 128] = w4.w;
      }
    }

    // xyz channels (0..5): direct coalesced scalar writes
    if (tid < 4 * KK) {
      int s4 = tid / KK;
      int n = sidx[base + tid];
      const float* p = xyz + ((size_t)b * NN + n) * 3;
      float x = p[0], y = p[1], z = p[2];
      int qq = b * SS + s0 + hf * 4 + s4;
      float cx = nxyz[qq * 3 + 0], cy = nxyz[qq * 3 + 1],
            cz = nxyz[qq * 3 + 2];
      size_t obase = ((size_t)(b * OC) * SS + s0 + hf * 4) * KK + tid;
      out[obase + 0 * cstr] = x;
      out[obase + 1 * cstr] = y;
      out[obase + 2 * cstr] = z;
      out[obase + 3 * cstr] = x - cx;
      out[obase + 4 * cstr] = y - cy;
      out[obase + 5 * cstr] = z - cz;
    }
    __syncthreads();

    // feature channel rows: float4 stores (row base 16B-aligned:
    // s0*KK = 264*blk, hf*4*KK = 0/132, cstr = 67584 -- all mult of 4)
    {
      float4* out4 = (float4*)(out + ((size_t)(b * OC + 6) * SS +
                                      s0 + hf * 4) * KK);
      const size_t cstr4 = cstr >> 2;   // 16896
      const int NJ4 = KK;               // 33 float4 per row
      for (int idx = tid; idx < CC * NJ4; idx += GT) {
        int c = idx / NJ4;
        int j4 = idx - c * NJ4;
        float4 v;
        v.x = sf[c][4 * j4 + 0];
        v.y = sf[c][4 * j4 + 1];
        v.z = sf[c][4 * j4 + 2];
        v.w = sf[c][4 * j4 + 3];
        out4[(size_t)c * cstr4 + j4] = v;
      }
    }
    __syncthreads();  // sf reused by next half
  }
}

// ---------------- legacy fallback kernels (small-ws paths) ----------------
__global__ __launch_bounds__(256) void qg_ballq(
    const float* __restrict__ xyz, const float* __restrict__ nxyz,
    int* __restrict__ wsidx) {
  int q = (int)((blockIdx.x * blockDim.x + threadIdx.x) >> 6);
  int lane = (int)(threadIdx.x & 63);
  int b = q / SS;
  const float* xb = xyz + (size_t)b * NN * 3;
  ball_query_wave(xb, nxyz[q * 3], nxyz[q * 3 + 1], nxyz[q * 3 + 2], lane,
                  wsidx + (size_t)q * NS);
}

__global__ __launch_bounds__(256) void qg_gather(
    const float* __restrict__ xyz, const float* __restrict__ nxyz,
    const float* __restrict__ feat, const int* __restrict__ fps,
    const int* __restrict__ wsidx, float* __restrict__ out) {
  unsigned t = blockIdx.x * 256u + threadIdx.x;
  const unsigned TOT = (unsigned)BB * OC * SS * KK;
  if (t >= TOT) return;
  unsigned k = t % KK;
  unsigned r = t / KK;
  unsigned s = r % SS;
  r /= SS;
  unsigned c = r % OC;
  unsigned b = r / OC;
  unsigned q = b * SS + s;
  int n = (k == 0) ? fps[q] : wsidx[(size_t)q * NS + (k - 1)];
  float v;
  if (c < 6) {
    unsigned cc = (c < 3) ? c : c - 3;
    v = xyz[((size_t)b * NN + (unsigned)n) * 3 + cc];
    if (c >= 3) v -= nxyz[q * 3 + cc];
  } else {
    v = feat[((size_t)b * CC + (c - 6)) * NN + (unsigned)n];
  }
  out[t] = v;
}

__global__ __launch_bounds__(256) void qg_fused(
    const float* __restrict__ xyz, const float* __restrict__ nxyz,
    const float* __restrict__ feat, const int* __restrict__ fps,
    float* __restrict__ out) {
  __shared__ int sidx[4][KK];
  int wv = (int)(threadIdx.x >> 6), lane = (int)(threadIdx.x & 63);
  int q = (int)blockIdx.x * 4 + wv;
  int b = q / SS, s = q % SS;
  const float* xb = xyz + (size_t)b * NN * 3;
  ball_query_wave(xb, nxyz[q * 3], nxyz[q * 3 + 1], nxyz[q * 3 + 2], lane,
                  &sidx[wv][1]);
  if (lane == 0) sidx[wv][0] = fps[q];
  __syncthreads();
  for (int f = lane; f < OC * KK; f += 64) {
    int c = f / KK, k = f - c * KK;
    int n = sidx[wv][k];
    float v;
    if (c < 6) {
      int cc = (c < 3) ? c : c - 3;
      v = xb[n * 3 + cc];
      if (c >= 3) v -= nxyz[q * 3 + cc];
    } else {
      v = feat[((size_t)b * CC + (c - 6)) * NN + n];
    }
    out[((size_t)((size_t)b * OC + c) * SS + s) * KK + k] = v;
  }
}

extern "C" void kernel_launch(void* const* d_in, const int* in_sizes, int n_in,
                              void* d_out, int out_size, void* d_ws, size_t ws_size,
                              hipStream_t stream) {
  const float* xyz  = (const float*)d_in[0];   // (B, N, 3)
  const float* nxyz = (const float*)d_in[1];   // (B, S, 3)
  const float* feat = (const float*)d_in[2];   // (B, C, N)
  const int*   fps  = (const int*)d_in[3];     // (B, S)
  float* out = (float*)d_out;                  // (B, 70, S, 33)

  const size_t ptsc_b  = (size_t)BB * 1024 * CCAP * sizeof(float4);  // 4 MiB
  const size_t cnt_b   = 32768;  // cnt 16KB (B*1024 ints) + ovf + slack
  const size_t featT_b = (size_t)BB * NN * CC * sizeof(float);       // 16.8 MB
  const size_t grid_need = ptsc_b + cnt_b + featT_b;

  const size_t idx_b = (size_t)BB * SS * NS * sizeof(int);  // fallback

  if (ws_size >= grid_need) {
    char* w = (char*)d_ws;
    float4* ptsc  = (float4*)w;                      w += ptsc_b;
    int*    cnt   = (int*)w;                         w += cnt_b;
    float*  featT = (float*)w;
    int*    ovf   = cnt + BB * 1024;  // 4 ints inside the zeroed region
    (void)hipMemsetAsync(cnt, 0, cnt_b, stream);
    qg_tr_build<<<512, 256, 0, stream>>>(xyz, feat, featT, cnt, ovf, ptsc);
    qg_main<<<BB * (SS / SCH), GT, 0, stream>>>(xyz, nxyz, ptsc, cnt, ovf,
                                                featT, fps, out);
  } else if (ws_size >= idx_b) {
    int* wsidx = (int*)d_ws;
    qg_ballq<<<(BB * SS) / 4, 256, 0, stream>>>(xyz, nxyz, wsidx);
    unsigned tot = (unsigned)BB * OC * SS * KK;
    qg_gather<<<(tot + 255u) / 256u, 256, 0, stream>>>(xyz, nxyz, feat, fps,
                                                       wsidx, out);
  } else {
    qg_fused<<<(BB * SS) / 4, 256, 0, stream>>>(xyz, nxyz, feat, fps, out);
  }
}

// Round 20
// 48.797 us; speedup vs baseline: 1.0049x; 1.0049x over previous
//
#include <hip/hip_runtime.h>

#define BB 4
#define NN 16384
#define SS 2048
#define CC 64
#define NS 32
#define KK 33   // NS + 1 (fps_idx prepended)
#define OC 70   // 3 raw xyz + 3 centered xyz + 64 features
#define SCH 8   // s-chunk per main block (8 queries, 1 wave each)
#define GT 512  // main block threads
#define NC 10
#define NCELL 1000
#define CCAP 64          // fixed per-cell capacity (avg 16.4, Poisson tail ~0)
#define HCAP 128         // per-wave hit buffer (avg 62, ~8 sigma; exact fallback)
#define RPAD 0.100001f   // cell-range pad (covers fp rounding of d2 test)

// --- prevent fma contraction so d2 matches the np/jax fp32 reference ---
__device__ __forceinline__ float sq_nofma(float v) {
  float r = v * v;
  asm volatile("" : "+v"(r));
  return r;
}

__device__ __forceinline__ int cell1(float x) {
  int c = (int)(x * 10.0f);
  return c < 0 ? 0 : (c > 9 ? 9 : c);
}
__device__ __forceinline__ int cell3(float x, float y, float z) {
  return (cell1(z) * NC + cell1(y)) * NC + cell1(x);
}

// ---------------- legacy wave ball-query (fallback + overflow path) -------
__device__ __forceinline__ void ball_query_wave(
    const float* __restrict__ xb, float qx, float qy, float qz, int lane,
    int* out) {
  const float R2 = 0.01f;
  int cnt = 0;
  int firstIdx = 0;
  for (int base = 0; base < NN; base += 256) {
    float px[4], py[4], pz[4];
#pragma unroll
    for (int j = 0; j < 4; ++j) {
      int n = base + j * 64 + lane;
      const float* p = xb + n * 3;
      px[j] = p[0]; py[j] = p[1]; pz[j] = p[2];
    }
#pragma unroll
    for (int j = 0; j < 4; ++j) {
      float dx = px[j] - qx, dy = py[j] - qy, dz = pz[j] - qz;
      float d2 = sq_nofma(dx) + sq_nofma(dy);
      asm volatile("" : "+v"(d2));
      d2 = d2 + sq_nofma(dz);
      bool m = d2 < R2;
      unsigned long long bal = __ballot(m);
      if (cnt == 0 && bal) firstIdx = base + j * 64 + __builtin_ctzll(bal);
      int pos = cnt + (int)__popcll(bal & ((1ull << lane) - 1ull));
      if (m && pos < NS) out[pos] = base + j * 64 + lane;
      cnt += (int)__popcll(bal);
    }
    if (cnt >= NS) break;
  }
  if (cnt < NS) {
    int pad = (cnt == 0) ? 0 : firstIdx;
    if (lane >= cnt && lane < NS) out[lane] = pad;
  }
}

// ---------------- K1: float4 transpose + direct fixed-capacity scatter ----
// (verified R10-R14: build side + memset + gaps = ~11.6us total)
__global__ __launch_bounds__(256) void qg_tr_build(
    const float* __restrict__ xyz, const float* __restrict__ feat,
    float* __restrict__ featT, int* __restrict__ cnt, int* __restrict__ ovf,
    float4* __restrict__ ptsc) {
  __shared__ float tile[32 * 260];  // 32 rows, stride 260 (pad kills conflicts)
  const int bid = (int)blockIdx.x;
  const int tid = (int)threadIdx.x;
  const int b = bid >> 7;
  const int rest = bid & 127;
  const int n0 = (rest >> 1) << 8;  // 0,256,...,16128
  const int cc = rest & 1;
  const int c0 = cc << 5;  // 0 or 32
  const int wv = tid >> 6, lane = tid & 63;

  if (cc == 0) {  // direct scatter of this block's 256 points
    const int n = n0 + tid;
    const float* p = xyz + ((size_t)b * NN + n) * 3;
    float x = p[0], y = p[1], z = p[2];
    int cell = cell3(x, y, z);
    int pos = atomicAdd(&cnt[(b << 10) + cell], 1);
    if (pos < CCAP) {
      ptsc[((((size_t)b << 10) + cell) << 6) + pos] =
          make_float4(x, y, z, __int_as_float(n));
    } else {
      atomicOr(&ovf[b], 1);
    }
  }

  const float* fb = feat + ((size_t)b * CC + c0) * NN + n0;
#pragma unroll
  for (int rr = 0; rr < 8; ++rr) {
    int c = rr * 4 + wv;  // 0..31
    float4 v = *(const float4*)(fb + (size_t)c * NN + 4 * lane);
    *(float4*)&tile[c * 260 + 4 * lane] = v;
  }
  __syncthreads();
  const int c4 = lane & 7, m = lane >> 3;
  float4* oT = (float4*)(featT + ((size_t)b * NN + n0) * CC);
#pragma unroll
  for (int it = 0; it < 8; ++it) {
    int n = it * 32 + wv * 8 + m;  // 0..255
    float4 v;
    v.x = tile[(4 * c4 + 0) * 260 + n];
    v.y = tile[(4 * c4 + 1) * 260 + n];
    v.z = tile[(4 * c4 + 2) * 260 + n];
    v.w = tile[(4 * c4 + 3) * 260 + n];
    oT[(size_t)n * (CC / 4) + (c0 >> 2) + c4] = v;
  }
}

// ---------------- K2: fused cell ball-query + gather -----------------------
// 1024 blocks (XCD-swizzled), 8 queries/block, one wave per query with
// barrier-free private rank; phases 2/3 twice over s-halves reusing sf;
// phase-3 stores widened to float4.
__global__ __launch_bounds__(GT) void qg_main(
    const float* __restrict__ xyz, const float* __restrict__ nxyz,
    const float4* __restrict__ ptsc, const int* __restrict__ cnt,
    const int* __restrict__ ovf, const float* __restrict__ featT,
    const int* __restrict__ fps, float* __restrict__ out) {
  __shared__ float sf[CC][4 * KK + 1];  // [64][133] padded: 0 bank conflicts
  __shared__ int sidx[SCH * KK];        // 264
  __shared__ int hitbuf[8][HCAP];
  const int tid = (int)threadIdx.x;
  const int raw = (int)blockIdx.x;               // 0..1023
  const int blk = (raw & 7) * 128 + (raw >> 3);  // bijective: 1024 = 8*128
  const int b = blk >> 8;
  const int s0 = (blk & 255) * SCH;
  const int wv = tid >> 6, lane = tid & 63;
  const int q = b * SS + s0 + wv;  // one query per wave
  const float R2 = 0.01f;
  const float qx = nxyz[q * 3 + 0];
  const float qy = nxyz[q * 3 + 1];
  const float qz = nxyz[q * 3 + 2];
  int* hb = hitbuf[wv];
  int* qout = &sidx[wv * KK];
  const bool bad = ovf[b] != 0;

  // ---- phase 1: ball query, fully per-wave (no inter-wave sync) ----
  if (bad) {
    // cell-capacity overflow (prob ~0): exact legacy linear scan
    ball_query_wave(xyz + (size_t)b * NN * 3, qx, qy, qz, lane, qout + 1);
  } else {
    int lox = max(0, (int)floorf((qx - RPAD) * 10.f));
    int hix = min(9, (int)floorf((qx + RPAD) * 10.f));
    int loy = max(0, (int)floorf((qy - RPAD) * 10.f));
    int hiy = min(9, (int)floorf((qy + RPAD) * 10.f));
    int loz = max(0, (int)floorf((qz - RPAD) * 10.f));
    int hiz = min(9, (int)floorf((qz + RPAD) * 10.f));
    const int ncx = hix - lox + 1, ncy = hiy - loy + 1, ncz = hiz - loz + 1;
    const int ncell = ncx * ncy * ncz;  // 1..27

    // hoist: lane i < ncell owns cell i (row-major over z,y,x)
    const int* cntb = cnt + (b << 10);
    int cell_l = 0, cnt_l = 0;
    if (lane < ncell) {
      int iz = lane / (ncx * ncy);
      int r = lane - iz * ncx * ncy;
      int iy = r / ncx, ix = r - iy * ncx;
      cell_l = ((loz + iz) * NC + (loy + iy)) * NC + (lox + ix);
      cnt_l = cntb[cell_l];
    }

    const float4* pcb = ptsc + ((size_t)b << 16);
    const unsigned long long lt = (1ull << lane) - 1ull;
    const int slot = lane & 31;
    const int half = lane >> 5;  // 0: first cell of pair, 1: second
    const int npair = (ncell + 1) >> 1;
    int hcnt = 0;

#define PAIRLOAD(pp)                                                       \
  ({                                                                       \
    int pc_ = ((pp) < npair) ? (pp) : 0;                                   \
    int ca_ = __shfl(cell_l, 2 * pc_, 64);                                 \
    int cb_ = __shfl(cell_l, 2 * pc_ + 1, 64);                             \
    pcb[(((half ? cb_ : ca_)) << 6) + slot];                               \
  })

    float4 v0 = PAIRLOAD(0);
    float4 v1 = PAIRLOAD(1);
    for (int p = 0; p < npair; ++p) {
      float4 v = v0;
      v0 = v1;
      v1 = PAIRLOAD(p + 2);
      int m0 = __shfl(cnt_l, 2 * p, 64);
      int m1 = __shfl(cnt_l, 2 * p + 1, 64);
      int m = half ? m1 : m0;
      {
        float dx = v.x - qx, dy = v.y - qy, dz = v.z - qz;
        float d2 = sq_nofma(dx) + sq_nofma(dy);
        asm volatile("" : "+v"(d2));
        d2 = d2 + sq_nofma(dz);
        bool hit = (slot < m) && (d2 < R2);
        unsigned long long bal = __ballot(hit);
        if (hit) {
          int pos = hcnt + (int)__popcll(bal & lt);
          if (pos < HCAP) hb[pos] = __float_as_int(v.w);
        }
        hcnt += (int)__popcll(bal);
      }
      if (m0 > 32 || m1 > 32) {  // rare (P ~ 6e-5 per cell), wave-uniform
        int ca = __shfl(cell_l, 2 * p, 64);
        int cb = __shfl(cell_l, 2 * p + 1, 64);
        float4 w = pcb[(((half ? cb : ca)) << 6) + 32 + slot];
        float dx = w.x - qx, dy = w.y - qy, dz = w.z - qz;
        float d2 = sq_nofma(dx) + sq_nofma(dy);
        asm volatile("" : "+v"(d2));
        d2 = d2 + sq_nofma(dz);
        bool hit = (32 + slot < m) && (d2 < R2);
        unsigned long long bal = __ballot(hit);
        if (hit) {
          int pos = hcnt + (int)__popcll(bal & lt);
          if (pos < HCAP) hb[pos] = __float_as_int(w.w);
        }
        hcnt += (int)__popcll(bal);
      }
    }
#undef PAIRLOAD

    asm volatile("s_waitcnt lgkmcnt(0)" ::: "memory");  // hb visible wave-wide
    const int M = hcnt;  // wave-uniform (ballot-accumulated)
    if (M > HCAP) {
      // hit-buffer overflow safety net: exact legacy linear scan
      ball_query_wave(xyz + (size_t)b * NN * 3, qx, qy, qz, lane, qout + 1);
    } else {
      // rank by original index = output position (order-independent)
      int minv = 0x7fffffff;
      for (int i = lane; i < M; i += 64) {
        int hh = hb[i];
        minv = min(minv, hh);
        int rank = 0;
        for (int j = 0; j < M; ++j) rank += (hb[j] < hh) ? 1 : 0;
        if (rank < NS) qout[1 + rank] = hh;
      }
      if (M < NS) {
#pragma unroll
        for (int d = 1; d < 64; d <<= 1)
          minv = min(minv, __shfl_xor(minv, d, 64));
        int pad = (M == 0) ? 0 : minv;
        if (lane >= M && lane < NS) qout[1 + lane] = pad;
      }
    }
  }
  if (lane == 0) qout[0] = fps[q];
  __syncthreads();

  // ---- phases 2/3 twice over s-halves, reusing sf ----
  const size_t cstr = (size_t)SS * KK;
  const float4* fT4 = (const float4*)(featT + (size_t)b * NN * CC);
#pragma unroll
  for (int hf = 0; hf < 2; ++hf) {
    const int base = hf * 4 * KK;  // 0 or 132
    // gather features -> padded LDS (hoisted idx + 5 independent loads)
    {
      const int e = tid & 15;
      const int g = tid >> 4;  // 0..31
      const bool has4 = (g + 128) < 4 * KK;
      int n0_ = sidx[base + g];
      int n1_ = sidx[base + g + 32];
      int n2_ = sidx[base + g + 64];
      int n3_ = sidx[base + g + 96];
      int n4_ = has4 ? sidx[base + g + 128] : 0;
      float4 w0 = fT4[(size_t)n0_ * (CC / 4) + e];
      float4 w1 = fT4[(size_t)n1_ * (CC / 4) + e];
      float4 w2 = fT4[(size_t)n2_ * (CC / 4) + e];
      float4 w3 = fT4[(size_t)n3_ * (CC / 4) + e];
      float4 w4 = has4 ? fT4[(size_t)n4_ * (CC / 4) + e]
                       : make_float4(0.f, 0.f, 0.f, 0.f);
      sf[4 * e + 0][g] = w0.x;
      sf[4 * e + 1][g] = w0.y;
      sf[4 * e + 2][g] = w0.z;
      sf[4 * e + 3][g] = w0.w;
      sf[4 * e + 0][g + 32] = w1.x;
      sf[4 * e + 1][g + 32] = w1.y;
      sf[4 * e + 2][g + 32] = w1.z;
      sf[4 * e + 3][g + 32] = w1.w;
      sf[4 * e + 0][g + 64] = w2.x;
      sf[4 * e + 1][g + 64] = w2.y;
      sf[4 * e + 2][g + 64] = w2.z;
      sf[4 * e + 3][g + 64] = w2.w;
      sf[4 * e + 0][g + 96] = w3.x;
      sf[4 * e + 1][g + 96] = w3.y;
      sf[4 * e + 2][g + 96] = w3.z;
      sf[4 * e + 3][g + 96] = w3.w;
      if (has4) {
        sf[4 * e + 0][g + 128] = w4.x;
        sf[4 * e + 1][g + 128] = w4.y;
        sf[4 * e + 2][g + 128] = w4.z;
        sf[4 * e + 3][g + 128] = w4.w;
      }
    }

    // xyz channels (0..5): direct coalesced scalar writes
    if (tid < 4 * KK) {
      int s4 = tid / KK;
      int n = sidx[base + tid];
      const float* p = xyz + ((size_t)b * NN + n) * 3;
      float x = p[0], y = p[1], z = p[2];
      int qq = b * SS + s0 + hf * 4 + s4;
      float cx = nxyz[qq * 3 + 0], cy = nxyz[qq * 3 + 1],
            cz = nxyz[qq * 3 + 2];
      size_t obase = ((size_t)(b * OC) * SS + s0 + hf * 4) * KK + tid;
      out[obase + 0 * cstr] = x;
      out[obase + 1 * cstr] = y;
      out[obase + 2 * cstr] = z;
      out[obase + 3 * cstr] = x - cx;
      out[obase + 4 * cstr] = y - cy;
      out[obase + 5 * cstr] = z - cz;
    }
    __syncthreads();

    // feature channel rows: float4 stores (row base 16B-aligned:
    // s0*KK = 264*blk, hf*4*KK = 0/132, cstr = 67584 -- all mult of 4)
    {
      float4* out4 = (float4*)(out + ((size_t)(b * OC + 6) * SS +
                                      s0 + hf * 4) * KK);
      const size_t cstr4 = cstr >> 2;   // 16896
      const int NJ4 = KK;               // 33 float4 per row
      for (int idx = tid; idx < CC * NJ4; idx += GT) {
        int c = idx / NJ4;
        int j4 = idx - c * NJ4;
        float4 v;
        v.x = sf[c][4 * j4 + 0];
        v.y = sf[c][4 * j4 + 1];
        v.z = sf[c][4 * j4 + 2];
        v.w = sf[c][4 * j4 + 3];
        out4[(size_t)c * cstr4 + j4] = v;
      }
    }
    __syncthreads();  // sf reused by next half
  }
}

// ---------------- legacy fallback kernels (small-ws paths) ----------------
__global__ __launch_bounds__(256) void qg_ballq(
    const float* __restrict__ xyz, const float* __restrict__ nxyz,
    int* __restrict__ wsidx) {
  int q = (int)((blockIdx.x * blockDim.x + threadIdx.x) >> 6);
  int lane = (int)(threadIdx.x & 63);
  int b = q / SS;
  const float* xb = xyz + (size_t)b * NN * 3;
  ball_query_wave(xb, nxyz[q * 3], nxyz[q * 3 + 1], nxyz[q * 3 + 2], lane,
                  wsidx + (size_t)q * NS);
}

__global__ __launch_bounds__(256) void qg_gather(
    const float* __restrict__ xyz, const float* __restrict__ nxyz,
    const float* __restrict__ feat, const int* __restrict__ fps,
    const int* __restrict__ wsidx, float* __restrict__ out) {
  unsigned t = blockIdx.x * 256u + threadIdx.x;
  const unsigned TOT = (unsigned)BB * OC * SS * KK;
  if (t >= TOT) return;
  unsigned k = t % KK;
  unsigned r = t / KK;
  unsigned s = r % SS;
  r /= SS;
  unsigned c = r % OC;
  unsigned b = r / OC;
  unsigned q = b * SS + s;
  int n = (k == 0) ? fps[q] : wsidx[(size_t)q * NS + (k - 1)];
  float v;
  if (c < 6) {
    unsigned cc = (c < 3) ? c : c - 3;
    v = xyz[((size_t)b * NN + (unsigned)n) * 3 + cc];
    if (c >= 3) v -= nxyz[q * 3 + cc];
  } else {
    v = feat[((size_t)b * CC + (c - 6)) * NN + (unsigned)n];
  }
  out[t] = v;
}

__global__ __launch_bounds__(256) void qg_fused(
    const float* __restrict__ xyz, const float* __restrict__ nxyz,
    const float* __restrict__ feat, const int* __restrict__ fps,
    float* __restrict__ out) {
  __shared__ int sidx[4][KK];
  int wv = (int)(threadIdx.x >> 6), lane = (int)(threadIdx.x & 63);
  int q = (int)blockIdx.x * 4 + wv;
  int b = q / SS, s = q % SS;
  const float* xb = xyz + (size_t)b * NN * 3;
  ball_query_wave(xb, nxyz[q * 3], nxyz[q * 3 + 1], nxyz[q * 3 + 2], lane,
                  &sidx[wv][1]);
  if (lane == 0) sidx[wv][0] = fps[q];
  __syncthreads();
  for (int f = lane; f < OC * KK; f += 64) {
    int c = f / KK, k = f - c * KK;
    int n = sidx[wv][k];
    float v;
    if (c < 6) {
      int cc = (c < 3) ? c : c - 3;
      v = xb[n * 3 + cc];
      if (c >= 3) v -= nxyz[q * 3 + cc];
    } else {
      v = feat[((size_t)b * CC + (c - 6)) * NN + n];
    }
    out[((size_t)((size_t)b * OC + c) * SS + s) * KK + k] = v;
  }
}

extern "C" void kernel_launch(void* const* d_in, const int* in_sizes, int n_in,
                              void* d_out, int out_size, void* d_ws, size_t ws_size,
                              hipStream_t stream) {
  const float* xyz  = (const float*)d_in[0];   // (B, N, 3)
  const float* nxyz = (const float*)d_in[1];   // (B, S, 3)
  const float* feat = (const float*)d_in[2];   // (B, C, N)
  const int*   fps  = (const int*)d_in[3];     // (B, S)
  float* out = (float*)d_out;                  // (B, 70, S, 33)

  const size_t ptsc_b  = (size_t)BB * 1024 * CCAP * sizeof(float4);  // 4 MiB
  const size_t cnt_b   = 32768;  // cnt 16KB (B*1024 ints) + ovf + slack
  const size_t featT_b = (size_t)BB * NN * CC * sizeof(float);       // 16.8 MB
  const size_t grid_need = ptsc_b + cnt_b + featT_b;

  const size_t idx_b = (size_t)BB * SS * NS * sizeof(int);  // fallback

  if (ws_size >= grid_need) {
    char* w = (char*)d_ws;
    float4* ptsc  = (float4*)w;                      w += ptsc_b;
    int*    cnt   = (int*)w;                         w += cnt_b;
    float*  featT = (float*)w;
    int*    ovf   = cnt + BB * 1024;  // 4 ints inside the zeroed region
    (void)hipMemsetAsync(cnt, 0, cnt_b, stream);
    qg_tr_build<<<512, 256, 0, stream>>>(xyz, feat, featT, cnt, ovf, ptsc);
    qg_main<<<BB * (SS / SCH), GT, 0, stream>>>(xyz, nxyz, ptsc, cnt, ovf,
                                                featT, fps, out);
  } else if (ws_size >= idx_b) {
    int* wsidx = (int*)d_ws;
    qg_ballq<<<(BB * SS) / 4, 256, 0, stream>>>(xyz, nxyz, wsidx);
    unsigned tot = (unsigned)BB * OC * SS * KK;
    qg_gather<<<(tot + 255u) / 256u, 256, 0, stream>>>(xyz, nxyz, feat, fps,
                                                       wsidx, out);
  } else {
    qg_fused<<<(BB * SS) / 4, 256, 0, stream>>>(xyz, nxyz, feat, fps, out);
  }
}